// Round 8
// baseline (243.688 us; speedup 1.0000x reference)
//
#include <hip/hip_runtime.h>

typedef __attribute__((ext_vector_type(8))) __bf16 bf16x8;
typedef __attribute__((ext_vector_type(4))) float f32x4;

__device__ __forceinline__ ushort f2b(float f) {
    uint u = __builtin_bit_cast(uint, f);
    u += 0x7fffu + ((u >> 16) & 1u);
    return (ushort)(u >> 16);
}
__device__ __forceinline__ float b2f(ushort h) {
    uint u = ((uint)h) << 16;
    return __builtin_bit_cast(float, u);
}

// ---------------- cast f32 -> bf16 (vec4) ----------------
__global__ __launch_bounds__(256) void cast_kernel(const float* __restrict__ src,
                                                   ushort* __restrict__ dst) {
    size_t i = ((size_t)blockIdx.x * 256 + threadIdx.x) * 4;
    float4 v = *(const float4*)(src + i);
    ushort4 o;
    o.x = f2b(v.x); o.y = f2b(v.y); o.z = f2b(v.z); o.w = f2b(v.w);
    *(ushort4*)(dst + i) = o;
}

// ---------------- cast + ROW-PERMUTE w_aoa so (a_j, g_j) output columns pair up ----------------
// dst row n' = src row q(n') = ((n'&63) | ((n'>>7)<<6)) + 1024*((n'>>6)&1)
__global__ __launch_bounds__(256) void cast_permute_aoa(const float* __restrict__ src,
                                                        ushort* __restrict__ dst) {
    int n1 = blockIdx.x >> 1;
    int c = (blockIdx.x & 1) * 1024 + threadIdx.x * 4;
    int q = ((n1 & 63) | ((n1 >> 7) << 6)) + ((n1 >> 6) & 1) * 1024;
    float4 v = *(const float4*)(src + (size_t)q * 2048 + c);
    ushort4 o;
    o.x = f2b(v.x); o.y = f2b(v.y); o.z = f2b(v.z); o.w = f2b(v.w);
    *(ushort4*)(dst + (size_t)n1 * 2048 + c) = o;
}

// ---------------- LayerNorm(query) -> bf16 into xq[:,1024:2048] ----------------
__global__ __launch_bounds__(256) void ln_kernel(const float* __restrict__ x,
                                                 const float* __restrict__ ga,
                                                 const float* __restrict__ be,
                                                 ushort* __restrict__ xq) {
    const int row = blockIdx.x, tid = threadIdx.x;
    __shared__ float red[4];
    float4 v = ((const float4*)(x + (size_t)row * 1024))[tid];
    float sm = v.x + v.y + v.z + v.w;
    for (int off = 32; off; off >>= 1) sm += __shfl_xor(sm, off);
    if ((tid & 63) == 0) red[tid >> 6] = sm;
    __syncthreads();
    float mean = (red[0] + red[1] + red[2] + red[3]) * (1.f / 1024.f);
    __syncthreads();
    float dx = v.x - mean, dy = v.y - mean, dz = v.z - mean, dw = v.w - mean;
    float s2 = dx * dx + dy * dy + dz * dz + dw * dw;
    for (int off = 32; off; off >>= 1) s2 += __shfl_xor(s2, off);
    if ((tid & 63) == 0) red[tid >> 6] = s2;
    __syncthreads();
    float var = (red[0] + red[1] + red[2] + red[3]) * (1.f / 1023.f);
    float inv = 1.f / (sqrtf(var) + 1e-6f);
    float4 g = ((const float4*)ga)[tid];
    float4 bb = ((const float4*)be)[tid];
    ushort4 o;
    o.x = f2b(g.x * dx * inv + bb.x);
    o.y = f2b(g.y * dy * inv + bb.y);
    o.z = f2b(g.z * dz * inv + bb.z);
    o.w = f2b(g.w * dw * inv + bb.w);
    *(ushort4*)&xq[(size_t)row * 2048 + 1024 + tid * 4] = o;
}

// ---------------- GEMM v5: 256x256, BK=64, 4-phase per-phase-stage + vmcnt(4) (R6-proven) ----------------
// MODE 0: fused QKV. N=3072 over regions {Q,K,V}; A selected per region; outputs
//   Qb/Kb row-major bf16 (Q scaled by qscale) and Vt transposed (B,H,128,S).
// MODE 1: AOA + fused GLU. B = permuted w_aoa; out f32 (M x 1024) = a*sigmoid(g).
// Per K-tile t (sel=t&1), phases consume quadrants [(aL,bL),(aH,bL),(aH,bH),(aL,bH)]
// while staging half-tiles of t+1 in order [AL,BL,AH,BH], one per phase, with
// s_waitcnt vmcnt(4) after each MM (2-3 phases of flight per load; retirement
// order verified: AL by end-ph3(t-1), BL by end-ph3, AH by end-ph0(t), BH by end-ph1(t)).
template <int MODE>
__global__ __launch_bounds__(512, 2) void gemm5(const ushort* __restrict__ Aq, int ldaq,
                                                const ushort* __restrict__ Ak,
                                                const ushort* __restrict__ Av,
                                                const ushort* __restrict__ B, int ldb,
                                                const float* __restrict__ bias0,
                                                const float* __restrict__ bias1,
                                                const float* __restrict__ bias2,
                                                void* __restrict__ out0,
                                                void* __restrict__ out1,
                                                void* __restrict__ out2,
                                                int K, int NB, float qscale) {
    __shared__ ushort lds[2][32768];   // per buf: A 256x64 (32KB) | B 256x64 (32KB)

    const int tid = threadIdx.x;
    const int w = tid >> 6, l = tid & 63;
    const int wr = w >> 2, wcn = w & 3;
    const int r16 = l & 15, g4 = l >> 4;

    const int bid = blockIdx.x;
    const int cpx = gridDim.x >> 3;
    const int swz = (bid & 7) * cpx + (bid >> 3);
    const int m0 = (swz / NB) * 256;
    const int n0 = (swz % NB) * 256;

    // region select (wave-uniform). MODE1: region 0 semantics with A=Aq.
    const int region = (MODE == 0) ? (n0 >> 10) : 0;
    const ushort* A = (MODE == 0) ? (region == 0 ? Aq : (region == 1 ? Ak : Av)) : Aq;
    const int lda = (MODE == 0) ? (region == 0 ? ldaq : 1024) : ldaq;

    const int srow8 = l >> 3;
    const int sxor8 = ((l & 7) ^ srow8) * 8;
    const ushort* As0 = A + (size_t)(m0 + w * 8 + srow8) * lda + sxor8;
    const ushort* Bs0 = B + (size_t)(n0 + w * 8 + srow8) * ldb + sxor8;

    f32x4 acc[8][4];
#pragma unroll
    for (int i = 0; i < 8; i++)
#pragma unroll
        for (int j = 0; j < 4; j++) acc[i][j] = (f32x4){0.f, 0.f, 0.f, 0.f};

    const int sw16 = (r16 & 7) << 4;
    char* ldsb = (char*)&lds[0][0];

    // stage half-tile HS (0=AL,1=BL,2=AH,3=BH) of K-tile kt into buffer sel
#define STAGE_H(sel_, HS_, kt_)                                                            \
    do {                                                                                   \
        const int mat_ = (HS_)&1, half_ = (HS_) >> 1;                                      \
        const ushort* sb_ = mat_ ? Bs0 : As0;                                              \
        const int ld_ = mat_ ? ldb : lda;                                                  \
        _Pragma("unroll") for (int li_ = 0; li_ < 2; li_++) {                              \
            const ushort* src_ = sb_ + (size_t)(half_ * 128 + li_ * 64) * ld_ + (kt_)*64;  \
            int dst_ = (sel_)*65536 + mat_ * 32768 + half_ * 16384 + li_ * 8192 + w * 1024;\
            __builtin_amdgcn_global_load_lds(                                              \
                (const __attribute__((address_space(1))) void*)src_,                       \
                (__attribute__((address_space(3))) void*)(ldsb + dst_), 16, 0, 0);         \
        }                                                                                  \
    } while (0)

    auto LDA4 = [&](bf16x8 (&dst)[4][2], int sel, int half) {
#pragma unroll
        for (int ai = 0; ai < 4; ai++)
#pragma unroll
            for (int ks = 0; ks < 2; ks++)
                dst[ai][ks] = *(const bf16x8*)(ldsb + sel * 65536 + half * 16384 +
                                               (wr * 16 + 32 * ai + r16) * 128 +
                                               ((ks * 64 + g4 * 16) ^ sw16));
    };
    auto LDB2 = [&](bf16x8 (&dst)[2][2], int sel, int half) {
#pragma unroll
        for (int bi = 0; bi < 2; bi++)
#pragma unroll
            for (int ks = 0; ks < 2; ks++)
                dst[bi][ks] = *(const bf16x8*)(ldsb + sel * 65536 + 32768 + half * 16384 +
                                               (wcn * 16 + 64 * bi + r16) * 128 +
                                               ((ks * 64 + g4 * 16) ^ sw16));
    };
    auto MM = [&](bf16x8 (&af)[4][2], bf16x8 (&bf)[2][2], int A0, int B0) {
        __builtin_amdgcn_s_setprio(1);
#pragma unroll
        for (int ks = 0; ks < 2; ks++)
#pragma unroll
            for (int ai = 0; ai < 4; ai++)
#pragma unroll
                for (int bi = 0; bi < 2; bi++)
                    acc[A0 + ai][B0 + bi] = __builtin_amdgcn_mfma_f32_16x16x32_bf16(
                        af[ai][ks], bf[bi][ks], acc[A0 + ai][B0 + bi], 0, 0, 0);
        __builtin_amdgcn_s_setprio(0);
    };

    const int NT = K >> 6;

    STAGE_H(0, 0, 0); STAGE_H(0, 1, 0); STAGE_H(0, 2, 0); STAGE_H(0, 3, 0);
    asm volatile("s_waitcnt vmcnt(0)" ::: "memory");
    __builtin_amdgcn_s_barrier();

    bf16x8 aL[4][2], aH[4][2], bL[2][2], bH[2][2];

    for (int t = 0; t < NT; ++t) {
        const int sel = t & 1;
        const bool pf = (t + 1 < NT);
        // phase 0: (aL,bL)
        LDA4(aL, sel, 0); LDB2(bL, sel, 0);
        if (pf) STAGE_H(sel ^ 1, 0, t + 1);
        __builtin_amdgcn_s_barrier();
        MM(aL, bL, 0, 0);
        asm volatile("s_waitcnt vmcnt(4)" ::: "memory");
        __builtin_amdgcn_s_barrier();
        // phase 1: (aH,bL)
        LDA4(aH, sel, 1);
        if (pf) STAGE_H(sel ^ 1, 1, t + 1);
        __builtin_amdgcn_s_barrier();
        MM(aH, bL, 4, 0);
        asm volatile("s_waitcnt vmcnt(4)" ::: "memory");
        __builtin_amdgcn_s_barrier();
        // phase 2: (aH,bH)
        LDB2(bH, sel, 1);
        if (pf) STAGE_H(sel ^ 1, 2, t + 1);
        __builtin_amdgcn_s_barrier();
        MM(aH, bH, 4, 2);
        asm volatile("s_waitcnt vmcnt(4)" ::: "memory");
        __builtin_amdgcn_s_barrier();
        // phase 3: (aL,bH) — no new reads
        if (pf) STAGE_H(sel ^ 1, 3, t + 1);
        __builtin_amdgcn_s_barrier();
        MM(aL, bH, 0, 2);
        asm volatile("s_waitcnt vmcnt(4)" ::: "memory");
        __builtin_amdgcn_s_barrier();
    }
#undef STAGE_H

    if (MODE == 1) {
        // fused GLU epilogue: pairs (2bp, 2bp+1) -> out column j
        float* out = (float*)out0;
#pragma unroll
        for (int bp = 0; bp < 2; bp++) {
            int j = (n0 >> 1) + wcn * 16 + 64 * bp + r16;
            float bsa = bias0[j];
            float bsg = bias0[j + 1024];
#pragma unroll
            for (int a_ = 0; a_ < 8; a_++) {
                int mr = m0 + wr * 16 + 32 * a_ + g4 * 4;
#pragma unroll
                for (int r = 0; r < 4; r++) {
                    float av = acc[a_][2 * bp][r] + bsa;
                    float gv = acc[a_][2 * bp + 1][r] + bsg;
                    out[(size_t)(mr + r) * 1024 + j] = av * (1.f / (1.f + __expf(-gv)));
                }
            }
        }
    } else {
        const int nr0 = n0 & 1023;
        const float* bias = region == 0 ? bias0 : (region == 1 ? bias1 : bias2);
        const float scale = region == 0 ? qscale : 1.f;
        if (region < 2) {
            ushort* C = (ushort*)(region == 0 ? out0 : out1);
#pragma unroll
            for (int b_ = 0; b_ < 4; b_++) {
                int n = nr0 + wcn * 16 + 64 * b_ + r16;
                float bs = bias[n];
#pragma unroll
                for (int a_ = 0; a_ < 8; a_++) {
                    int mr = m0 + wr * 16 + 32 * a_ + g4 * 4;
#pragma unroll
                    for (int r = 0; r < 4; r++)
                        C[(size_t)(mr + r) * 1024 + n] = f2b((acc[a_][b_][r] + bs) * scale);
                }
            }
        } else {
            // V region: Vt[(b*8+h)*128 + d][s]
            ushort* Vt = (ushort*)out2;
#pragma unroll
            for (int b_ = 0; b_ < 4; b_++) {
                int n = nr0 + wcn * 16 + 64 * b_ + r16;
                float bs = bias[n];
                int h = n >> 7, d = n & 127;
#pragma unroll
                for (int a_ = 0; a_ < 8; a_++) {
                    int mr = m0 + wr * 16 + 32 * a_ + g4 * 4;
                    int bb = mr >> 10, s_ = mr & 1023;
                    ushort4 o;
                    o.x = f2b(acc[a_][b_][0] + bs);
                    o.y = f2b(acc[a_][b_][1] + bs);
                    o.z = f2b(acc[a_][b_][2] + bs);
                    o.w = f2b(acc[a_][b_][3] + bs);
                    *(ushort4*)&Vt[((size_t)(bb * 8 + h) * 128 + d) * 1024 + s_] = o;
                }
            }
        }
    }
}

// ---------------- flash attention v5: swapped-operand + deferred-PV pipeline ----------------
__global__ __launch_bounds__(512, 4) void attn_kernel(const ushort* __restrict__ Q,
                                                      const ushort* __restrict__ Kt,
                                                      const ushort* __restrict__ Vt,
                                                      const int* __restrict__ mask,
                                                      ushort* __restrict__ xq) {
    __shared__ ushort Ks[2][8192];   // [64 kv][128 d], row=256B, XOR swz ((row&7)<<4 bytes)
    __shared__ ushort Vs[2][8192];   // [128 d][64 s],  row=128B, XOR swz ((d&7)<<4 bytes)
    __shared__ ushort Pl[8][1024];   // per-wave [16 q][64 kv], 128B rows, XOR swz ((q&7)<<4 bytes)

    const int tid = threadIdx.x;
    const int l = tid & 63, wid = tid >> 6;
    const int r16 = l & 15, g4 = l >> 4;
    const int id = blockIdx.x;
    const int bh = ((id >> 6) << 3) | (id & 7);
    const int qb = (id >> 3) & 7;
    const int b = bh >> 3, h = bh & 7;
    const int q0 = qb * 128 + wid * 16;

    bf16x8 qf[4];
    const ushort* Qrow = Q + (size_t)(b * 1024 + q0 + r16) * 1024 + h * 128 + g4 * 8;
#pragma unroll
    for (int kf = 0; kf < 4; kf++) qf[kf] = *(const bf16x8*)(Qrow + kf * 32);

    const ushort* Kg = Kt + ((size_t)b * 1024) * 1024 + h * 128;
    const ushort* Vg = Vt + (size_t)(b * 8 + h) * 128 * 1024;
    const int* mptr = mask + b * 1024;

    f32x4 xacc[8];
#pragma unroll
    for (int i = 0; i < 8; i++) xacc[i] = (f32x4){0.f, 0.f, 0.f, 0.f};
    float mrow = -INFINITY, lrow = 0.f, sclp = 0.f;

    char* Pme = (char*)&Pl[wid][0];
    const int pswz = (r16 & 7) << 4;

    auto STAGE_K = [&](int sel, int t) {
        const int kv0 = t * 64;
#pragma unroll
        for (int it = 0; it < 2; ++it) {
            int ob = it * 8192 + wid * 1024;
            int o = ob + l * 16;
            int row = o >> 8;
            int sc = (o & 255) ^ ((row & 7) << 4);
            const ushort* src = Kg + (size_t)(kv0 + row) * 1024 + (sc >> 1);
            __builtin_amdgcn_global_load_lds((const __attribute__((address_space(1))) void*)src,
                (__attribute__((address_space(3))) void*)((char*)&Ks[sel][0] + ob), 16, 0, 0);
        }
    };
    auto STAGE_V = [&](int sel, int t) {
        const int kv0 = t * 64;
#pragma unroll
        for (int it = 0; it < 2; ++it) {
            int ob = it * 8192 + wid * 1024;
            int o = ob + l * 16;
            int d = o >> 7;
            int sc = (o & 127) ^ ((d & 7) << 4);
            const ushort* src = Vg + (size_t)d * 1024 + kv0 + (sc >> 1);
            __builtin_amdgcn_global_load_lds((const __attribute__((address_space(1))) void*)src,
                (__attribute__((address_space(3))) void*)((char*)&Vs[sel][0] + ob), 16, 0, 0);
        }
    };

    auto QK = [&](f32x4 (&s)[4], int sel, unsigned long long wt) {
        const char* Kb_ = (const char*)&Ks[sel][0];
#pragma unroll
        for (int cg = 0; cg < 4; cg++) {
            s[cg] = (f32x4){0.f, 0.f, 0.f, 0.f};
            const int rowk = cg * 16 + r16;
            const char* kr = Kb_ + rowk * 256;
            const int sw = (rowk & 7) << 4;
            __builtin_amdgcn_s_setprio(1);
#pragma unroll
            for (int kf = 0; kf < 4; kf++) {
                bf16x8 kfr = *(const bf16x8*)(kr + ((kf * 64 + g4 * 16) ^ sw));
                s[cg] = __builtin_amdgcn_mfma_f32_16x16x32_bf16(kfr, qf[kf], s[cg], 0, 0, 0);
            }
            __builtin_amdgcn_s_setprio(0);
            uint nib = (uint)(wt >> (cg * 16 + g4 * 4)) & 15u;
#pragma unroll
            for (int r = 0; r < 4; r++)
                if (!((nib >> r) & 1u)) s[cg][r] = -1e9f;
        }
    };
    auto PV = [&](int sel) {
        const char* Vb_ = (const char*)&Vs[sel][0];
        bf16x8 pfr[2];
#pragma unroll
        for (int ks = 0; ks < 2; ks++)
            pfr[ks] = *(const bf16x8*)(Pme + r16 * 128 + ((g4 * 16 + ks * 64) ^ pswz));
#pragma unroll
        for (int cg2 = 0; cg2 < 8; cg2++)
#pragma unroll
            for (int r = 0; r < 4; r++) xacc[cg2][r] *= sclp;
        __builtin_amdgcn_s_setprio(1);
#pragma unroll
        for (int ks = 0; ks < 2; ks++) {
#pragma unroll
            for (int cg2 = 0; cg2 < 8; cg2++) {
                const int d = cg2 * 16 + r16;
                bf16x8 vfr = *(const bf16x8*)(Vb_ + d * 128 + ((ks * 64 + g4 * 16) ^ ((d & 7) << 4)));
                xacc[cg2] = __builtin_amdgcn_mfma_f32_16x16x32_bf16(vfr, pfr[ks], xacc[cg2], 0, 0, 0);
            }
        }
        __builtin_amdgcn_s_setprio(0);
    };
    auto SOFTMAX = [&](f32x4 (&s)[4]) {
        float pmax = -INFINITY;
#pragma unroll
        for (int cg = 0; cg < 4; cg++)
#pragma unroll
            for (int r = 0; r < 4; r++) pmax = fmaxf(pmax, s[cg][r]);
        pmax = fmaxf(pmax, __shfl_xor(pmax, 16));
        pmax = fmaxf(pmax, __shfl_xor(pmax, 32));
        float mn = fmaxf(mrow, pmax);
        sclp = __expf(mrow - mn);
        mrow = mn;
        float rsum = 0.f;
#pragma unroll
        for (int cg = 0; cg < 4; cg++)
#pragma unroll
            for (int r = 0; r < 4; r++) {
                float p = __expf(s[cg][r] - mn);
                s[cg][r] = p;
                rsum += p;
            }
        rsum += __shfl_xor(rsum, 16);
        rsum += __shfl_xor(rsum, 32);
        lrow = lrow * sclp + rsum;
#pragma unroll
        for (int cg = 0; cg < 4; cg++) {
            uint lo = ((uint)f2b(s[cg][1]) << 16) | f2b(s[cg][0]);
            uint hi = ((uint)f2b(s[cg][3]) << 16) | f2b(s[cg][2]);
            uint2 pk; pk.x = lo; pk.y = hi;
            *(uint2*)(Pme + r16 * 128 + ((cg * 32 + g4 * 8) ^ pswz)) = pk;
        }
    };

    STAGE_K(0, 0);
    int mv = mptr[l];
    asm volatile("s_waitcnt vmcnt(0)" ::: "memory");
    __syncthreads();
    STAGE_K(1, 1);
    STAGE_V(0, 0);
    unsigned long long wt = __ballot(mv != 0);
    mv = mptr[64 + l];
    {
        f32x4 s0[4];
        QK(s0, 0, wt);
        SOFTMAX(s0);
    }
    int kc = 1, vc = 0;

    for (int u = 1; u < 16; ++u) {
        wt = __ballot(mv != 0);
        asm volatile("s_waitcnt vmcnt(0)" ::: "memory");
        __syncthreads();
        if (u < 15) STAGE_K(kc ^ 1, u + 1);
        STAGE_V(vc ^ 1, u);
        if (u < 15) mv = mptr[(u + 1) * 64 + l];

        f32x4 sn[4];
        QK(sn, kc, wt);
        PV(vc);
        SOFTMAX(sn);

        kc ^= 1; vc ^= 1;
    }

    asm volatile("s_waitcnt vmcnt(0)" ::: "memory");
    __syncthreads();
    PV(vc);

    const float inv = 1.f / lrow;
    const size_t orow = (size_t)(b * 1024 + q0 + r16) * 2048 + h * 128;
#pragma unroll
    for (int cg2 = 0; cg2 < 8; cg2++) {
#pragma unroll
        for (int r = 0; r < 4; r++) {
            xq[orow + cg2 * 16 + g4 * 4 + r] = f2b(xacc[cg2][r] * inv);
        }
    }
}

extern "C" void kernel_launch(void* const* d_in, const int* in_sizes, int n_in,
                              void* d_out, int out_size, void* d_ws, size_t ws_size,
                              hipStream_t stream) {
    const float* query = (const float*)d_in[0];
    const float* value = (const float*)d_in[1];
    const float* key   = (const float*)d_in[2];
    const int*   mask  = (const int*)d_in[3];
    const float* ln_a  = (const float*)d_in[4];
    const float* ln_b  = (const float*)d_in[5];
    const float* wq    = (const float*)d_in[6];
    const float* bq    = (const float*)d_in[7];
    const float* wk    = (const float*)d_in[8];
    const float* bk    = (const float*)d_in[9];
    const float* wv    = (const float*)d_in[10];
    const float* bv    = (const float*)d_in[11];
    const float* waoa  = (const float*)d_in[12];
    const float* baoa  = (const float*)d_in[13];
    float* out = (float*)d_out;

    char* w8 = (char*)d_ws;
    ushort* xq   = (ushort*)(w8);                 // 8192x2048 bf16 ([x | q_ln])
    ushort* Qb   = (ushort*)(w8 + 33554432);      // 8192x1024 bf16
    ushort* Kb   = (ushort*)(w8 + 50331648);      // 8192x1024 bf16
    ushort* Vt   = (ushort*)(w8 + 67108864);      // (B,H,128,S) bf16
    ushort* keyb = (ushort*)(w8 + 83886080);      // 8192x1024 bf16
    ushort* valb = (ushort*)(w8 + 100663296);     // 8192x1024 bf16
    ushort* wqb  = (ushort*)(w8 + 117440512);     // 3x 1024x1024 bf16, CONTIGUOUS (wq|wk|wv)
    ushort* wkb  = (ushort*)(w8 + 119537664);
    ushort* wvb  = (ushort*)(w8 + 121634816);
    ushort* wab  = (ushort*)(w8 + 123731968);     // 2048x2048 bf16 (PERMUTED)

    cast_kernel<<<8192, 256, 0, stream>>>(key, keyb);
    cast_kernel<<<8192, 256, 0, stream>>>(value, valb);
    cast_kernel<<<1024, 256, 0, stream>>>(wq, wqb);
    cast_kernel<<<1024, 256, 0, stream>>>(wk, wkb);
    cast_kernel<<<1024, 256, 0, stream>>>(wv, wvb);
    cast_permute_aoa<<<4096, 256, 0, stream>>>(waoa, wab);
    ln_kernel<<<8192, 256, 0, stream>>>(query, ln_a, ln_b, xq);

    const float qscale = 0.08838834764831845f; // 1/sqrt(128)

    // fused QKV: M=8192, N=3072 (Q|K|V regions), K=1024 -> 32x12 = 384 blocks
    gemm5<0><<<384, 512, 0, stream>>>(xq + 1024, 2048, keyb, valb,
                                      wqb, 1024, bq, bk, bv,
                                      Qb, Kb, Vt, 1024, 12, qscale);

    attn_kernel<<<512, 512, 0, stream>>>(Qb, Kb, Vt, mask, xq);

    // AOA + GLU fused: M=8192, N=2048 (permuted), K=2048 -> 256 blocks
    gemm5<1><<<256, 512, 0, stream>>>(xq, 2048, nullptr, nullptr,
                                      wab, 2048, baoa, nullptr, nullptr,
                                      out, nullptr, nullptr, 2048, 8, 1.f);
}

// Round 9
// 236.334 us; speedup vs baseline: 1.0311x; 1.0311x over previous
//
#include <hip/hip_runtime.h>

typedef __attribute__((ext_vector_type(8))) __bf16 bf16x8;
typedef __attribute__((ext_vector_type(4))) float f32x4;

__device__ __forceinline__ ushort f2b(float f) {
    uint u = __builtin_bit_cast(uint, f);
    u += 0x7fffu + ((u >> 16) & 1u);
    return (ushort)(u >> 16);
}
__device__ __forceinline__ float b2f(ushort h) {
    uint u = ((uint)h) << 16;
    return __builtin_bit_cast(float, u);
}

// ---------------- cast f32 -> bf16 (vec4) ----------------
__global__ __launch_bounds__(256) void cast_kernel(const float* __restrict__ src,
                                                   ushort* __restrict__ dst) {
    size_t i = ((size_t)blockIdx.x * 256 + threadIdx.x) * 4;
    float4 v = *(const float4*)(src + i);
    ushort4 o;
    o.x = f2b(v.x); o.y = f2b(v.y); o.z = f2b(v.z); o.w = f2b(v.w);
    *(ushort4*)(dst + i) = o;
}

// ---------------- cast + ROW-PERMUTE w_aoa so (a_j, g_j) output columns pair up ----------------
__global__ __launch_bounds__(256) void cast_permute_aoa(const float* __restrict__ src,
                                                        ushort* __restrict__ dst) {
    int n1 = blockIdx.x >> 1;
    int c = (blockIdx.x & 1) * 1024 + threadIdx.x * 4;
    int q = ((n1 & 63) | ((n1 >> 7) << 6)) + ((n1 >> 6) & 1) * 1024;
    float4 v = *(const float4*)(src + (size_t)q * 2048 + c);
    ushort4 o;
    o.x = f2b(v.x); o.y = f2b(v.y); o.z = f2b(v.z); o.w = f2b(v.w);
    *(ushort4*)(dst + (size_t)n1 * 2048 + c) = o;
}

// ---------------- LayerNorm(query) -> bf16 into xq[:,1024:2048] ----------------
__global__ __launch_bounds__(256) void ln_kernel(const float* __restrict__ x,
                                                 const float* __restrict__ ga,
                                                 const float* __restrict__ be,
                                                 ushort* __restrict__ xq) {
    const int row = blockIdx.x, tid = threadIdx.x;
    __shared__ float red[4];
    float4 v = ((const float4*)(x + (size_t)row * 1024))[tid];
    float sm = v.x + v.y + v.z + v.w;
    for (int off = 32; off; off >>= 1) sm += __shfl_xor(sm, off);
    if ((tid & 63) == 0) red[tid >> 6] = sm;
    __syncthreads();
    float mean = (red[0] + red[1] + red[2] + red[3]) * (1.f / 1024.f);
    __syncthreads();
    float dx = v.x - mean, dy = v.y - mean, dz = v.z - mean, dw = v.w - mean;
    float s2 = dx * dx + dy * dy + dz * dz + dw * dw;
    for (int off = 32; off; off >>= 1) s2 += __shfl_xor(s2, off);
    if ((tid & 63) == 0) red[tid >> 6] = s2;
    __syncthreads();
    float var = (red[0] + red[1] + red[2] + red[3]) * (1.f / 1023.f);
    float inv = 1.f / (sqrtf(var) + 1e-6f);
    float4 g = ((const float4*)ga)[tid];
    float4 bb = ((const float4*)be)[tid];
    ushort4 o;
    o.x = f2b(g.x * dx * inv + bb.x);
    o.y = f2b(g.y * dy * inv + bb.y);
    o.z = f2b(g.z * dz * inv + bb.z);
    o.w = f2b(g.w * dw * inv + bb.w);
    *(ushort4*)&xq[(size_t)row * 2048 + 1024 + tid * 4] = o;
}

// ---------------- GEMM v6: 256x256, BK=64, DEEP pipeline (5-6 phases flight, vmcnt(10)) ----------------
// MODE 0: fused QKV (N=3072 regions Q,K,V; V stored transposed).  MODE 1: AOA + fused GLU.
// Frag-reuse frees buf[sel] regions progressively (AL after ph0, AH after ph1, BH after ph2),
// so tile t+2 streams into buf[sel] DURING tile t: issues (t+1,BH)@ph0, (t+2,AL)@ph1,
// (t+2,BL)@ph2, (t+2,AH)@ph3. Gates: vmcnt(10) at ph0/ph1/ph3 (ph2 gate-free).
// Invariant: 10 loads outstanding entering each tile. Last two tiles peeled (10/8/4, 2/0).
template <int MODE>
__global__ __launch_bounds__(512, 2) void gemm6(const ushort* __restrict__ Aq, int ldaq,
                                                const ushort* __restrict__ Ak,
                                                const ushort* __restrict__ Av,
                                                const ushort* __restrict__ B, int ldb,
                                                const float* __restrict__ bias0,
                                                const float* __restrict__ bias1,
                                                const float* __restrict__ bias2,
                                                void* __restrict__ out0,
                                                void* __restrict__ out1,
                                                void* __restrict__ out2,
                                                int K, int NB, float qscale) {
    __shared__ ushort lds[2][32768];   // per buf: A 256x64 (32KB) | B 256x64 (32KB)

    const int tid = threadIdx.x;
    const int w = tid >> 6, l = tid & 63;
    const int wr = w >> 2, wcn = w & 3;
    const int r16 = l & 15, g4 = l >> 4;

    const int bid = blockIdx.x;
    const int cpx = gridDim.x >> 3;
    const int swz = (bid & 7) * cpx + (bid >> 3);
    const int m0 = (swz / NB) * 256;
    const int n0 = (swz % NB) * 256;

    const int region = (MODE == 0) ? (n0 >> 10) : 0;
    const ushort* A = (MODE == 0) ? (region == 0 ? Aq : (region == 1 ? Ak : Av)) : Aq;
    const int lda = (MODE == 0) ? (region == 0 ? ldaq : 1024) : ldaq;

    const int srow8 = l >> 3;
    const int sxor8 = ((l & 7) ^ srow8) * 8;
    const ushort* As0 = A + (size_t)(m0 + w * 8 + srow8) * lda + sxor8;
    const ushort* Bs0 = B + (size_t)(n0 + w * 8 + srow8) * ldb + sxor8;

    f32x4 acc[8][4];
#pragma unroll
    for (int i = 0; i < 8; i++)
#pragma unroll
        for (int j = 0; j < 4; j++) acc[i][j] = (f32x4){0.f, 0.f, 0.f, 0.f};

    const int sw16 = (r16 & 7) << 4;
    char* ldsb = (char*)&lds[0][0];

    // stage half-tile HS (0=AL,1=BL,2=AH,3=BH) of K-tile kt into buffer sel (2 loads)
#define STAGE_H(sel_, HS_, kt_)                                                            \
    do {                                                                                   \
        const int mat_ = (HS_)&1, half_ = (HS_) >> 1;                                      \
        const ushort* sb_ = mat_ ? Bs0 : As0;                                              \
        const int ld_ = mat_ ? ldb : lda;                                                  \
        _Pragma("unroll") for (int li_ = 0; li_ < 2; li_++) {                              \
            const ushort* src_ = sb_ + (size_t)(half_ * 128 + li_ * 64) * ld_ + (kt_)*64;  \
            int dst_ = (sel_)*65536 + mat_ * 32768 + half_ * 16384 + li_ * 8192 + w * 1024;\
            __builtin_amdgcn_global_load_lds(                                              \
                (const __attribute__((address_space(1))) void*)src_,                       \
                (__attribute__((address_space(3))) void*)(ldsb + dst_), 16, 0, 0);         \
        }                                                                                  \
    } while (0)

    auto LDA4 = [&](bf16x8 (&dst)[4][2], int sel, int half) {
#pragma unroll
        for (int ai = 0; ai < 4; ai++)
#pragma unroll
            for (int ks = 0; ks < 2; ks++)
                dst[ai][ks] = *(const bf16x8*)(ldsb + sel * 65536 + half * 16384 +
                                               (wr * 16 + 32 * ai + r16) * 128 +
                                               ((ks * 64 + g4 * 16) ^ sw16));
    };
    auto LDB2 = [&](bf16x8 (&dst)[2][2], int sel, int half) {
#pragma unroll
        for (int bi = 0; bi < 2; bi++)
#pragma unroll
            for (int ks = 0; ks < 2; ks++)
                dst[bi][ks] = *(const bf16x8*)(ldsb + sel * 65536 + 32768 + half * 16384 +
                                               (wcn * 16 + 64 * bi + r16) * 128 +
                                               ((ks * 64 + g4 * 16) ^ sw16));
    };
    auto MM = [&](bf16x8 (&af)[4][2], bf16x8 (&bf)[2][2], int A0, int B0) {
        __builtin_amdgcn_s_setprio(1);
#pragma unroll
        for (int ks = 0; ks < 2; ks++)
#pragma unroll
            for (int ai = 0; ai < 4; ai++)
#pragma unroll
                for (int bi = 0; bi < 2; bi++)
                    acc[A0 + ai][B0 + bi] = __builtin_amdgcn_mfma_f32_16x16x32_bf16(
                        af[ai][ks], bf[bi][ks], acc[A0 + ai][B0 + bi], 0, 0, 0);
        __builtin_amdgcn_s_setprio(0);
    };

    const int NT = K >> 6;

    // prologue: tile0 full + tile1 {AL,BL,AH} = 14 loads; retire tile0 {AL,BL}
    STAGE_H(0, 0, 0); STAGE_H(0, 1, 0); STAGE_H(0, 2, 0); STAGE_H(0, 3, 0);
    STAGE_H(1, 0, 1); STAGE_H(1, 1, 1); STAGE_H(1, 2, 1);
    asm volatile("s_waitcnt vmcnt(10)" ::: "memory");
    __builtin_amdgcn_s_barrier();

    bf16x8 aL[4][2], aH[4][2], bL[2][2], bH[2][2];

    for (int t = 0; t < NT - 2; ++t) {
        const int sel = t & 1;
        // ph0: read aL,bL | issue (t+1,BH)
        LDA4(aL, sel, 0); LDB2(bL, sel, 0);
        STAGE_H(sel ^ 1, 3, t + 1);
        __builtin_amdgcn_s_barrier();
        MM(aL, bL, 0, 0);
        asm volatile("s_waitcnt vmcnt(10)" ::: "memory");   // (t,AH) landed
        __builtin_amdgcn_s_barrier();
        // ph1: read aH | issue (t+2,AL) into buf[sel] (AL region dead since ph0)
        LDA4(aH, sel, 1);
        STAGE_H(sel, 0, t + 2);
        __builtin_amdgcn_s_barrier();
        MM(aH, bL, 4, 0);
        asm volatile("s_waitcnt vmcnt(10)" ::: "memory");   // (t,BH) landed
        __builtin_amdgcn_s_barrier();
        // ph2: read bH | issue (t+2,BL) — NO gate
        LDB2(bH, sel, 1);
        STAGE_H(sel, 1, t + 2);
        __builtin_amdgcn_s_barrier();
        MM(aH, bH, 4, 2);
        __builtin_amdgcn_s_barrier();
        // ph3: issue (t+2,AH)
        STAGE_H(sel, 2, t + 2);
        __builtin_amdgcn_s_barrier();
        MM(aL, bH, 0, 2);
        asm volatile("s_waitcnt vmcnt(10)" ::: "memory");   // (t+1,AL),(t+1,BL) landed
        __builtin_amdgcn_s_barrier();
    }
    {   // t = NT-2: only (NT-1,BH) still to issue
        const int sel = (NT - 2) & 1;
        LDA4(aL, sel, 0); LDB2(bL, sel, 0);
        STAGE_H(sel ^ 1, 3, NT - 1);
        __builtin_amdgcn_s_barrier();
        MM(aL, bL, 0, 0);
        asm volatile("s_waitcnt vmcnt(10)" ::: "memory");
        __builtin_amdgcn_s_barrier();
        LDA4(aH, sel, 1);
        __builtin_amdgcn_s_barrier();
        MM(aH, bL, 4, 0);
        asm volatile("s_waitcnt vmcnt(8)" ::: "memory");
        __builtin_amdgcn_s_barrier();
        LDB2(bH, sel, 1);
        __builtin_amdgcn_s_barrier();
        MM(aH, bH, 4, 2);
        __builtin_amdgcn_s_barrier();
        MM(aL, bH, 0, 2);
        asm volatile("s_waitcnt vmcnt(4)" ::: "memory");
        __builtin_amdgcn_s_barrier();
    }
    {   // t = NT-1: drain
        const int sel = (NT - 1) & 1;
        LDA4(aL, sel, 0); LDB2(bL, sel, 0);
        __builtin_amdgcn_s_barrier();
        MM(aL, bL, 0, 0);
        asm volatile("s_waitcnt vmcnt(2)" ::: "memory");
        __builtin_amdgcn_s_barrier();
        LDA4(aH, sel, 1);
        __builtin_amdgcn_s_barrier();
        MM(aH, bL, 4, 0);
        asm volatile("s_waitcnt vmcnt(0)" ::: "memory");
        __builtin_amdgcn_s_barrier();
        LDB2(bH, sel, 1);
        MM(aH, bH, 4, 2);
        MM(aL, bH, 0, 2);
    }
#undef STAGE_H

    if (MODE == 1) {
        float* out = (float*)out0;
#pragma unroll
        for (int bp = 0; bp < 2; bp++) {
            int j = (n0 >> 1) + wcn * 16 + 64 * bp + r16;
            float bsa = bias0[j];
            float bsg = bias0[j + 1024];
#pragma unroll
            for (int a_ = 0; a_ < 8; a_++) {
                int mr = m0 + wr * 16 + 32 * a_ + g4 * 4;
#pragma unroll
                for (int r = 0; r < 4; r++) {
                    float av = acc[a_][2 * bp][r] + bsa;
                    float gv = acc[a_][2 * bp + 1][r] + bsg;
                    out[(size_t)(mr + r) * 1024 + j] = av * (1.f / (1.f + __expf(-gv)));
                }
            }
        }
    } else {
        const int nr0 = n0 & 1023;
        const float* bias = region == 0 ? bias0 : (region == 1 ? bias1 : bias2);
        const float scale = region == 0 ? qscale : 1.f;
        if (region < 2) {
            ushort* C = (ushort*)(region == 0 ? out0 : out1);
#pragma unroll
            for (int b_ = 0; b_ < 4; b_++) {
                int n = nr0 + wcn * 16 + 64 * b_ + r16;
                float bs = bias[n];
#pragma unroll
                for (int a_ = 0; a_ < 8; a_++) {
                    int mr = m0 + wr * 16 + 32 * a_ + g4 * 4;
#pragma unroll
                    for (int r = 0; r < 4; r++)
                        C[(size_t)(mr + r) * 1024 + n] = f2b((acc[a_][b_][r] + bs) * scale);
                }
            }
        } else {
            ushort* Vt = (ushort*)out2;
#pragma unroll
            for (int b_ = 0; b_ < 4; b_++) {
                int n = nr0 + wcn * 16 + 64 * b_ + r16;
                float bs = bias[n];
                int h = n >> 7, d = n & 127;
#pragma unroll
                for (int a_ = 0; a_ < 8; a_++) {
                    int mr = m0 + wr * 16 + 32 * a_ + g4 * 4;
                    int bb = mr >> 10, s_ = mr & 1023;
                    ushort4 o;
                    o.x = f2b(acc[a_][b_][0] + bs);
                    o.y = f2b(acc[a_][b_][1] + bs);
                    o.z = f2b(acc[a_][b_][2] + bs);
                    o.w = f2b(acc[a_][b_][3] + bs);
                    *(ushort4*)&Vt[((size_t)(bb * 8 + h) * 128 + d) * 1024 + s_] = o;
                }
            }
        }
    }
}

// ---------------- flash attention v5: swapped-operand + deferred-PV pipeline ----------------
__global__ __launch_bounds__(512, 4) void attn_kernel(const ushort* __restrict__ Q,
                                                      const ushort* __restrict__ Kt,
                                                      const ushort* __restrict__ Vt,
                                                      const int* __restrict__ mask,
                                                      ushort* __restrict__ xq) {
    __shared__ ushort Ks[2][8192];
    __shared__ ushort Vs[2][8192];
    __shared__ ushort Pl[8][1024];

    const int tid = threadIdx.x;
    const int l = tid & 63, wid = tid >> 6;
    const int r16 = l & 15, g4 = l >> 4;
    const int id = blockIdx.x;
    const int bh = ((id >> 6) << 3) | (id & 7);
    const int qb = (id >> 3) & 7;
    const int b = bh >> 3, h = bh & 7;
    const int q0 = qb * 128 + wid * 16;

    bf16x8 qf[4];
    const ushort* Qrow = Q + (size_t)(b * 1024 + q0 + r16) * 1024 + h * 128 + g4 * 8;
#pragma unroll
    for (int kf = 0; kf < 4; kf++) qf[kf] = *(const bf16x8*)(Qrow + kf * 32);

    const ushort* Kg = Kt + ((size_t)b * 1024) * 1024 + h * 128;
    const ushort* Vg = Vt + (size_t)(b * 8 + h) * 128 * 1024;
    const int* mptr = mask + b * 1024;

    f32x4 xacc[8];
#pragma unroll
    for (int i = 0; i < 8; i++) xacc[i] = (f32x4){0.f, 0.f, 0.f, 0.f};
    float mrow = -INFINITY, lrow = 0.f, sclp = 0.f;

    char* Pme = (char*)&Pl[wid][0];
    const int pswz = (r16 & 7) << 4;

    auto STAGE_K = [&](int sel, int t) {
        const int kv0 = t * 64;
#pragma unroll
        for (int it = 0; it < 2; ++it) {
            int ob = it * 8192 + wid * 1024;
            int o = ob + l * 16;
            int row = o >> 8;
            int sc = (o & 255) ^ ((row & 7) << 4);
            const ushort* src = Kg + (size_t)(kv0 + row) * 1024 + (sc >> 1);
            __builtin_amdgcn_global_load_lds((const __attribute__((address_space(1))) void*)src,
                (__attribute__((address_space(3))) void*)((char*)&Ks[sel][0] + ob), 16, 0, 0);
        }
    };
    auto STAGE_V = [&](int sel, int t) {
        const int kv0 = t * 64;
#pragma unroll
        for (int it = 0; it < 2; ++it) {
            int ob = it * 8192 + wid * 1024;
            int o = ob + l * 16;
            int d = o >> 7;
            int sc = (o & 127) ^ ((d & 7) << 4);
            const ushort* src = Vg + (size_t)d * 1024 + kv0 + (sc >> 1);
            __builtin_amdgcn_global_load_lds((const __attribute__((address_space(1))) void*)src,
                (__attribute__((address_space(3))) void*)((char*)&Vs[sel][0] + ob), 16, 0, 0);
        }
    };

    auto QK = [&](f32x4 (&s)[4], int sel, unsigned long long wt) {
        const char* Kb_ = (const char*)&Ks[sel][0];
#pragma unroll
        for (int cg = 0; cg < 4; cg++) {
            s[cg] = (f32x4){0.f, 0.f, 0.f, 0.f};
            const int rowk = cg * 16 + r16;
            const char* kr = Kb_ + rowk * 256;
            const int sw = (rowk & 7) << 4;
            __builtin_amdgcn_s_setprio(1);
#pragma unroll
            for (int kf = 0; kf < 4; kf++) {
                bf16x8 kfr = *(const bf16x8*)(kr + ((kf * 64 + g4 * 16) ^ sw));
                s[cg] = __builtin_amdgcn_mfma_f32_16x16x32_bf16(kfr, qf[kf], s[cg], 0, 0, 0);
            }
            __builtin_amdgcn_s_setprio(0);
            uint nib = (uint)(wt >> (cg * 16 + g4 * 4)) & 15u;
#pragma unroll
            for (int r = 0; r < 4; r++)
                if (!((nib >> r) & 1u)) s[cg][r] = -1e9f;
        }
    };
    auto PV = [&](int sel) {
        const char* Vb_ = (const char*)&Vs[sel][0];
        bf16x8 pfr[2];
#pragma unroll
        for (int ks = 0; ks < 2; ks++)
            pfr[ks] = *(const bf16x8*)(Pme + r16 * 128 + ((g4 * 16 + ks * 64) ^ pswz));
#pragma unroll
        for (int cg2 = 0; cg2 < 8; cg2++)
#pragma unroll
            for (int r = 0; r < 4; r++) xacc[cg2][r] *= sclp;
        __builtin_amdgcn_s_setprio(1);
#pragma unroll
        for (int ks = 0; ks < 2; ks++) {
#pragma unroll
            for (int cg2 = 0; cg2 < 8; cg2++) {
                const int d = cg2 * 16 + r16;
                bf16x8 vfr = *(const bf16x8*)(Vb_ + d * 128 + ((ks * 64 + g4 * 16) ^ ((d & 7) << 4)));
                xacc[cg2] = __builtin_amdgcn_mfma_f32_16x16x32_bf16(vfr, pfr[ks], xacc[cg2], 0, 0, 0);
            }
        }
        __builtin_amdgcn_s_setprio(0);
    };
    auto SOFTMAX = [&](f32x4 (&s)[4]) {
        float pmax = -INFINITY;
#pragma unroll
        for (int cg = 0; cg < 4; cg++)
#pragma unroll
            for (int r = 0; r < 4; r++) pmax = fmaxf(pmax, s[cg][r]);
        pmax = fmaxf(pmax, __shfl_xor(pmax, 16));
        pmax = fmaxf(pmax, __shfl_xor(pmax, 32));
        float mn = fmaxf(mrow, pmax);
        sclp = __expf(mrow - mn);
        mrow = mn;
        float rsum = 0.f;
#pragma unroll
        for (int cg = 0; cg < 4; cg++)
#pragma unroll
            for (int r = 0; r < 4; r++) {
                float p = __expf(s[cg][r] - mn);
                s[cg][r] = p;
                rsum += p;
            }
        rsum += __shfl_xor(rsum, 16);
        rsum += __shfl_xor(rsum, 32);
        lrow = lrow * sclp + rsum;
#pragma unroll
        for (int cg = 0; cg < 4; cg++) {
            uint lo = ((uint)f2b(s[cg][1]) << 16) | f2b(s[cg][0]);
            uint hi = ((uint)f2b(s[cg][3]) << 16) | f2b(s[cg][2]);
            uint2 pk; pk.x = lo; pk.y = hi;
            *(uint2*)(Pme + r16 * 128 + ((cg * 32 + g4 * 8) ^ pswz)) = pk;
        }
    };

    STAGE_K(0, 0);
    int mv = mptr[l];
    asm volatile("s_waitcnt vmcnt(0)" ::: "memory");
    __syncthreads();
    STAGE_K(1, 1);
    STAGE_V(0, 0);
    unsigned long long wt = __ballot(mv != 0);
    mv = mptr[64 + l];
    {
        f32x4 s0[4];
        QK(s0, 0, wt);
        SOFTMAX(s0);
    }
    int kc = 1, vc = 0;

    for (int u = 1; u < 16; ++u) {
        wt = __ballot(mv != 0);
        asm volatile("s_waitcnt vmcnt(0)" ::: "memory");
        __syncthreads();
        if (u < 15) STAGE_K(kc ^ 1, u + 1);
        STAGE_V(vc ^ 1, u);
        if (u < 15) mv = mptr[(u + 1) * 64 + l];

        f32x4 sn[4];
        QK(sn, kc, wt);
        PV(vc);
        SOFTMAX(sn);

        kc ^= 1; vc ^= 1;
    }

    asm volatile("s_waitcnt vmcnt(0)" ::: "memory");
    __syncthreads();
    PV(vc);

    const float inv = 1.f / lrow;
    const size_t orow = (size_t)(b * 1024 + q0 + r16) * 2048 + h * 128;
#pragma unroll
    for (int cg2 = 0; cg2 < 8; cg2++) {
#pragma unroll
        for (int r = 0; r < 4; r++) {
            xq[orow + cg2 * 16 + g4 * 4 + r] = f2b(xacc[cg2][r] * inv);
        }
    }
}

extern "C" void kernel_launch(void* const* d_in, const int* in_sizes, int n_in,
                              void* d_out, int out_size, void* d_ws, size_t ws_size,
                              hipStream_t stream) {
    const float* query = (const float*)d_in[0];
    const float* value = (const float*)d_in[1];
    const float* key   = (const float*)d_in[2];
    const int*   mask  = (const int*)d_in[3];
    const float* ln_a  = (const float*)d_in[4];
    const float* ln_b  = (const float*)d_in[5];
    const float* wq    = (const float*)d_in[6];
    const float* bq    = (const float*)d_in[7];
    const float* wk    = (const float*)d_in[8];
    const float* bk    = (const float*)d_in[9];
    const float* wv    = (const float*)d_in[10];
    const float* bv    = (const float*)d_in[11];
    const float* waoa  = (const float*)d_in[12];
    const float* baoa  = (const float*)d_in[13];
    float* out = (float*)d_out;

    char* w8 = (char*)d_ws;
    ushort* xq   = (ushort*)(w8);                 // 8192x2048 bf16 ([x | q_ln])
    ushort* Qb   = (ushort*)(w8 + 33554432);      // 8192x1024 bf16
    ushort* Kb   = (ushort*)(w8 + 50331648);      // 8192x1024 bf16
    ushort* Vt   = (ushort*)(w8 + 67108864);      // (B,H,128,S) bf16
    ushort* keyb = (ushort*)(w8 + 83886080);      // 8192x1024 bf16
    ushort* valb = (ushort*)(w8 + 100663296);     // 8192x1024 bf16
    ushort* wqb  = (ushort*)(w8 + 117440512);     // 3x 1024x1024 bf16, CONTIGUOUS (wq|wk|wv)
    ushort* wkb  = (ushort*)(w8 + 119537664);
    ushort* wvb  = (ushort*)(w8 + 121634816);
    ushort* wab  = (ushort*)(w8 + 123731968);     // 2048x2048 bf16 (PERMUTED)

    cast_kernel<<<8192, 256, 0, stream>>>(key, keyb);
    cast_kernel<<<8192, 256, 0, stream>>>(value, valb);
    cast_kernel<<<1024, 256, 0, stream>>>(wq, wqb);
    cast_kernel<<<1024, 256, 0, stream>>>(wk, wkb);
    cast_kernel<<<1024, 256, 0, stream>>>(wv, wvb);
    cast_permute_aoa<<<4096, 256, 0, stream>>>(waoa, wab);
    ln_kernel<<<8192, 256, 0, stream>>>(query, ln_a, ln_b, xq);

    const float qscale = 0.08838834764831845f; // 1/sqrt(128)

    // fused QKV: M=8192, N=3072 (Q|K|V regions), K=1024 -> 384 blocks
    gemm6<0><<<384, 512, 0, stream>>>(xq + 1024, 2048, keyb, valb,
                                      wqb, 1024, bq, bk, bv,
                                      Qb, Kb, Vt, 1024, 12, qscale);

    attn_kernel<<<512, 512, 0, stream>>>(Qb, Kb, Vt, mask, xq);

    // AOA + GLU fused: M=8192, N=2048 (permuted), K=2048 -> 256 blocks
    gemm6<1><<<256, 512, 0, stream>>>(xq, 2048, nullptr, nullptr,
                                      wab, 2048, baoa, nullptr, nullptr,
                                      out, nullptr, nullptr, 2048, 8, 1.f);
}